// Round 1
// baseline (255.759 us; speedup 1.0000x reference)
//
#include <hip/hip_runtime.h>
#include <math.h>

// Problem: RetinaNet focal loss, B=8, A=65536, C=80, M=32.
// Memory-bound on classifications (167.8 MB). Single fused streaming pass.

static constexpr int   kC     = 80;    // classes (fixed by reference)
static constexpr int   kTA    = 256;   // anchors per block (A % 256 == 0)
static constexpr int   kBlock = 256;   // threads per block
static constexpr int   kMaxM  = 32;    // max gt boxes per image

// ---------------- workspace init (harness poisons ws with 0xAA) -------------
__global__ void init_ws_kernel(double* acc, int* pos, int B) {
    int t = threadIdx.x;
    if (t < B) { acc[t] = 0.0; acc[B + t] = 0.0; pos[t] = 0; }
}

// ---------------- per-element focal loss ------------------------------------
__device__ __forceinline__ float elem_loss(float c, int k, int f) {
    // f: assigned label if positive, -2 if negative (all-zero targets),
    //    (-1 = ignore, handled by caller).
    c = fminf(fmaxf(c, 1e-4f), 1.0f - 1e-4f);
    bool one = (k == f);
    float w = one ? (1.0f - c) : c;          // focal weight base
    float l = one ? c : (1.0f - c);          // bce argument
    // ALPHA = 0.5 -> alpha_factor is 0.5 for both branches.
    return 0.5f * w * w * (-__logf(l));
}

// ---------------- main kernel -----------------------------------------------
__global__ __launch_bounds__(kBlock) void focal_main(
        const float* __restrict__ cls,   // [B, A, C]
        const float* __restrict__ reg,   // [B, A, 4]
        const float* __restrict__ anc,   // [A, 4]
        const float* __restrict__ ann,   // [B, M, 5]
        double* __restrict__ cls_sum,    // [B]
        double* __restrict__ reg_sum,    // [B]
        int*    __restrict__ pos_cnt,    // [B]
        int A, int M)
{
    const int b  = blockIdx.y;
    const int a0 = blockIdx.x * kTA;
    const int t  = threadIdx.x;

    __shared__ float s_box[kMaxM][6];    // x1,y1,x2,y2,area,label
    __shared__ int   s_flag[kTA];        // label | -2 (neg) | -1 (ignore)

    if (t < M) {
        const float* p = ann + ((size_t)b * M + t) * 5;
        float x1 = p[0], y1 = p[1], x2 = p[2], y2 = p[3], lb = p[4];
        s_box[t][0] = x1; s_box[t][1] = y1;
        s_box[t][2] = x2; s_box[t][3] = y2;
        s_box[t][4] = (x2 - x1) * (y2 - y1);   // area_b
        s_box[t][5] = lb;
    }
    __syncthreads();

    // ---- phase 1: one anchor per thread: IoU argmax + flags + reg loss ----
    const int a = a0 + t;
    const float4 ab = *reinterpret_cast<const float4*>(anc + (size_t)a * 4);
    const float aw = ab.z - ab.x;
    const float ah = ab.w - ab.y;
    const float area_a = aw * ah;

    float best = -1.0f;
    int bestj = 0;
    #pragma unroll 8
    for (int j = 0; j < M; ++j) {
        float iw = fminf(ab.z, s_box[j][2]) - fmaxf(ab.x, s_box[j][0]);
        float ih = fminf(ab.w, s_box[j][3]) - fmaxf(ab.y, s_box[j][1]);
        iw = fmaxf(iw, 0.0f);
        ih = fmaxf(ih, 0.0f);
        float inter = iw * ih;
        float ua = fmaxf(area_a + s_box[j][4] - inter, 1e-8f);
        float iou = inter / ua;
        if (iou > best) { best = iou; bestj = j; }   // first-max semantics
    }
    const bool pos = (best >= 0.5f);
    const int flag = pos ? (int)s_box[bestj][5] : ((best < 0.4f) ? -2 : -1);
    s_flag[t] = flag;

    float regLoss = 0.0f;
    int   posInt  = pos ? 1 : 0;
    if (pos) {
        float gx1 = s_box[bestj][0], gy1 = s_box[bestj][1];
        float gx2 = s_box[bestj][2], gy2 = s_box[bestj][3];
        float gw = gx2 - gx1, gh = gy2 - gy1;
        float gcx = gx1 + 0.5f * gw, gcy = gy1 + 0.5f * gh;  // unclamped centers
        gw = fmaxf(gw, 1.0f);
        gh = fmaxf(gh, 1.0f);
        float acx = ab.x + 0.5f * aw, acy = ab.y + 0.5f * ah;
        float t0 = ((gcx - acx) / aw) / 0.1f;
        float t1 = ((gcy - acy) / ah) / 0.1f;
        float t2 = logf(gw / aw) / 0.2f;
        float t3 = logf(gh / ah) / 0.2f;
        const float4 rg = *reinterpret_cast<const float4*>(reg + ((size_t)b * A + a) * 4);
        float d0 = fabsf(t0 - rg.x), d1 = fabsf(t1 - rg.y);
        float d2 = fabsf(t2 - rg.z), d3 = fabsf(t3 - rg.w);
        const float th = 1.0f / 9.0f, csh = 0.5f / 9.0f;
        regLoss  = (d0 <= th) ? 4.5f * d0 * d0 : d0 - csh;
        regLoss += (d1 <= th) ? 4.5f * d1 * d1 : d1 - csh;
        regLoss += (d2 <= th) ? 4.5f * d2 * d2 : d2 - csh;
        regLoss += (d3 <= th) ? 4.5f * d3 * d3 : d3 - csh;
    }
    __syncthreads();

    // ---- phase 2: coalesced float4 stream over this block's cls tile ----
    const float4* cbase =
        reinterpret_cast<const float4*>(cls + ((size_t)b * A + a0) * kC);
    constexpr int F4A  = kC / 4;                    // 20 float4 per anchor
    constexpr int ITER = kTA * F4A / kBlock;        // 20 iterations
    float clsLoss = 0.0f;
    #pragma unroll 4
    for (int i = 0; i < ITER; ++i) {
        int idx = i * kBlock + t;                   // float4 index in tile
        int al  = idx / F4A;                        // local anchor
        int kb  = (idx - al * F4A) * 4;             // class base
        int f   = s_flag[al];
        float4 v = cbase[idx];
        if (f != -1) {
            clsLoss += elem_loss(v.x, kb + 0, f);
            clsLoss += elem_loss(v.y, kb + 1, f);
            clsLoss += elem_loss(v.z, kb + 2, f);
            clsLoss += elem_loss(v.w, kb + 3, f);
        }
    }

    // ---- block reduce (wave shuffle, then cross-wave via LDS) ----
    #pragma unroll
    for (int off = 32; off > 0; off >>= 1) {
        clsLoss += __shfl_down(clsLoss, off);
        regLoss += __shfl_down(regLoss, off);
        posInt  += __shfl_down(posInt,  off);
    }
    __shared__ float s_cls[kBlock / 64];
    __shared__ float s_reg[kBlock / 64];
    __shared__ int   s_pos[kBlock / 64];
    const int wid = t >> 6, lane = t & 63;
    if (lane == 0) { s_cls[wid] = clsLoss; s_reg[wid] = regLoss; s_pos[wid] = posInt; }
    __syncthreads();
    if (t == 0) {
        float cs = 0.0f, rs = 0.0f; int ps = 0;
        #pragma unroll
        for (int w = 0; w < kBlock / 64; ++w) { cs += s_cls[w]; rs += s_reg[w]; ps += s_pos[w]; }
        atomicAdd(&cls_sum[b], (double)cs);
        atomicAdd(&reg_sum[b], (double)rs);
        atomicAdd(&pos_cnt[b], ps);
    }
}

// ---------------- finalize ---------------------------------------------------
__global__ void finalize_kernel(const double* __restrict__ cls_sum,
                                const double* __restrict__ reg_sum,
                                const int* __restrict__ pos_cnt,
                                float* __restrict__ out, int B)
{
    if (threadIdx.x == 0 && blockIdx.x == 0) {
        double co = 0.0, ro = 0.0;
        for (int b = 0; b < B; ++b) {
            double np = (double)pos_cnt[b];
            co += cls_sum[b] / fmax(np, 1.0);
            ro += (pos_cnt[b] > 0) ? reg_sum[b] / (np * 4.0) : 0.0;
        }
        out[0] = (float)(co / B);
        out[1] = (float)(ro / B);
    }
}

// ---------------- launch -----------------------------------------------------
extern "C" void kernel_launch(void* const* d_in, const int* in_sizes, int n_in,
                              void* d_out, int out_size, void* d_ws, size_t ws_size,
                              hipStream_t stream)
{
    const float* cls = (const float*)d_in[0];   // [B, A, C]
    const float* reg = (const float*)d_in[1];   // [B, A, 4]
    const float* anc = (const float*)d_in[2];   // [1, A, 4]
    const float* ann = (const float*)d_in[3];   // [B, M, 5]

    const int A = in_sizes[2] / 4;
    const int B = in_sizes[1] / (A * 4);
    const int M = in_sizes[3] / (B * 5);        // <= kMaxM

    double* acc = (double*)d_ws;                // [B] cls_sum, [B] reg_sum
    int*    pos = (int*)(acc + 2 * B);
    float*  out = (float*)d_out;

    hipLaunchKernelGGL(init_ws_kernel, dim3(1), dim3(64), 0, stream, acc, pos, B);

    dim3 grid(A / kTA, B);                      // A % kTA == 0 for this problem
    hipLaunchKernelGGL(focal_main, grid, dim3(kBlock), 0, stream,
                       cls, reg, anc, ann, acc, acc + B, pos, A, M);

    hipLaunchKernelGGL(finalize_kernel, dim3(1), dim3(1), 0, stream,
                       acc, acc + B, pos, out, B);
}

// Round 3
// 248.245 us; speedup vs baseline: 1.0303x; 1.0303x over previous
//
#include <hip/hip_runtime.h>
#include <math.h>

// RetinaNet focal loss, B=8, A=65536, C=80, M=32.
// Memory-bound on classifications (167.8 MB). Fused streaming pass.
// R3 = R2 with the nontemporal loads done through native Clang vector
// types (HIP's float4 is a class -> rejected by __builtin_nontemporal_load).

typedef float f32x4 __attribute__((ext_vector_type(4)));

static constexpr int   kC     = 80;    // classes (fixed by reference)
static constexpr int   kTA    = 256;   // anchors per block (A % 256 == 0)
static constexpr int   kBlock = 256;   // threads per block
static constexpr int   kMaxM  = 32;    // max gt boxes per image
static constexpr int   kMaxB  = 16;    // max batch (actual 8)

// ---------------- per-element focal loss ------------------------------------
__device__ __forceinline__ float elem_loss(float c, int k, int f) {
    // f: assigned label if positive, -2 if negative (all-zero targets);
    //    ignore (-1) handled by caller.
    c = fminf(fmaxf(c, 1e-4f), 1.0f - 1e-4f);
    bool one = (k == f);
    float w = one ? (1.0f - c) : c;          // focal weight base
    float l = one ? c : (1.0f - c);          // bce argument
    // ALPHA = 0.5 -> alpha factor is 0.5 for both branches.
    return 0.5f * w * w * (-__logf(l));
}

// ---------------- main kernel -----------------------------------------------
__global__ __launch_bounds__(kBlock) void focal_main(
        const float* __restrict__ cls,   // [B, A, C]
        const float* __restrict__ reg,   // [B, A, 4]
        const float* __restrict__ anc,   // [A, 4]
        const float* __restrict__ ann,   // [B, M, 5]
        float* __restrict__ clsPart,     // [B * gridDim.x]
        float* __restrict__ regPart,     // [B * gridDim.x]
        int*   __restrict__ posPart,     // [B * gridDim.x]
        int A, int M)
{
    const int b  = blockIdx.y;
    const int a0 = blockIdx.x * kTA;
    const int t  = threadIdx.x;

    __shared__ float s_box[kMaxM][6];    // x1,y1,x2,y2,area,label
    __shared__ int   s_flag[kTA];        // label | -2 (neg) | -1 (ignore)

    if (t < M) {
        const float* p = ann + ((size_t)b * M + t) * 5;
        float x1 = p[0], y1 = p[1], x2 = p[2], y2 = p[3], lb = p[4];
        s_box[t][0] = x1; s_box[t][1] = y1;
        s_box[t][2] = x2; s_box[t][3] = y2;
        s_box[t][4] = (x2 - x1) * (y2 - y1);   // area_b
        s_box[t][5] = lb;
    }
    __syncthreads();

    // ---- phase 1: one anchor per thread: IoU argmax + flags + reg loss ----
    const int a = a0 + t;
    const f32x4 ab = *reinterpret_cast<const f32x4*>(anc + (size_t)a * 4);
    const float aw = ab.z - ab.x;
    const float ah = ab.w - ab.y;
    const float area_a = aw * ah;

    float best = -1.0f;
    int bestj = 0;
    #pragma unroll 8
    for (int j = 0; j < M; ++j) {
        float iw = fminf(ab.z, s_box[j][2]) - fmaxf(ab.x, s_box[j][0]);
        float ih = fminf(ab.w, s_box[j][3]) - fmaxf(ab.y, s_box[j][1]);
        iw = fmaxf(iw, 0.0f);
        ih = fmaxf(ih, 0.0f);
        float inter = iw * ih;
        float ua = fmaxf(area_a + s_box[j][4] - inter, 1e-8f);
        float iou = inter / ua;
        if (iou > best) { best = iou; bestj = j; }   // first-max semantics
    }
    const bool pos = (best >= 0.5f);
    const int flag = pos ? (int)s_box[bestj][5] : ((best < 0.4f) ? -2 : -1);
    s_flag[t] = flag;

    float regLoss = 0.0f;
    int   posInt  = pos ? 1 : 0;
    if (pos) {
        float gx1 = s_box[bestj][0], gy1 = s_box[bestj][1];
        float gx2 = s_box[bestj][2], gy2 = s_box[bestj][3];
        float gw = gx2 - gx1, gh = gy2 - gy1;
        float gcx = gx1 + 0.5f * gw, gcy = gy1 + 0.5f * gh;  // unclamped ctrs
        gw = fmaxf(gw, 1.0f);
        gh = fmaxf(gh, 1.0f);
        float acx = ab.x + 0.5f * aw, acy = ab.y + 0.5f * ah;
        float t0 = ((gcx - acx) / aw) / 0.1f;
        float t1 = ((gcy - acy) / ah) / 0.1f;
        float t2 = logf(gw / aw) / 0.2f;
        float t3 = logf(gh / ah) / 0.2f;
        const f32x4 rg = __builtin_nontemporal_load(
            reinterpret_cast<const f32x4*>(reg + ((size_t)b * A + a) * 4));
        float d0 = fabsf(t0 - rg.x), d1 = fabsf(t1 - rg.y);
        float d2 = fabsf(t2 - rg.z), d3 = fabsf(t3 - rg.w);
        const float th = 1.0f / 9.0f, csh = 0.5f / 9.0f;
        regLoss  = (d0 <= th) ? 4.5f * d0 * d0 : d0 - csh;
        regLoss += (d1 <= th) ? 4.5f * d1 * d1 : d1 - csh;
        regLoss += (d2 <= th) ? 4.5f * d2 * d2 : d2 - csh;
        regLoss += (d3 <= th) ? 4.5f * d3 * d3 : d3 - csh;
    }
    __syncthreads();

    // ---- phase 2: coalesced nontemporal f32x4 stream over cls tile ----
    const f32x4* cbase =
        reinterpret_cast<const f32x4*>(cls + ((size_t)b * A + a0) * kC);
    constexpr int F4A  = kC / 4;                    // 20 f32x4 per anchor
    constexpr int ITER = kTA * F4A / kBlock;        // 20 iterations
    float clsLoss = 0.0f;
    #pragma unroll 4
    for (int i = 0; i < ITER; ++i) {
        int idx = i * kBlock + t;                   // f32x4 index in tile
        int al  = idx / F4A;                        // local anchor
        int kb  = (idx - al * F4A) * 4;             // class base
        int f   = s_flag[al];
        f32x4 v = __builtin_nontemporal_load(&cbase[idx]);
        if (f != -1) {
            clsLoss += elem_loss(v.x, kb + 0, f);
            clsLoss += elem_loss(v.y, kb + 1, f);
            clsLoss += elem_loss(v.z, kb + 2, f);
            clsLoss += elem_loss(v.w, kb + 3, f);
        }
    }

    // ---- block reduce (wave shuffle, then cross-wave via LDS) ----
    #pragma unroll
    for (int off = 32; off > 0; off >>= 1) {
        clsLoss += __shfl_down(clsLoss, off);
        regLoss += __shfl_down(regLoss, off);
        posInt  += __shfl_down(posInt,  off);
    }
    __shared__ float s_cls[kBlock / 64];
    __shared__ float s_reg[kBlock / 64];
    __shared__ int   s_pos[kBlock / 64];
    const int wid = t >> 6, lane = t & 63;
    if (lane == 0) { s_cls[wid] = clsLoss; s_reg[wid] = regLoss; s_pos[wid] = posInt; }
    __syncthreads();
    if (t == 0) {
        float cs = 0.0f, rs = 0.0f; int ps = 0;
        #pragma unroll
        for (int w = 0; w < kBlock / 64; ++w) { cs += s_cls[w]; rs += s_reg[w]; ps += s_pos[w]; }
        const int part = b * gridDim.x + blockIdx.x;   // unique slot per block
        clsPart[part] = cs;
        regPart[part] = rs;
        posPart[part] = ps;
    }
}

// ---------------- finalize: reduce partials, write the two outputs ----------
__global__ void finalize_kernel(const float* __restrict__ clsPart,
                                const float* __restrict__ regPart,
                                const int*   __restrict__ posPart,
                                float* __restrict__ out,
                                int nPerImg, int B)
{
    const int w = threadIdx.x >> 6;     // wave id = image id
    const int l = threadIdx.x & 63;
    float cs = 0.0f, rs = 0.0f; int ps = 0;
    if (w < B) {
        for (int i = l; i < nPerImg; i += 64) {
            int idx = w * nPerImg + i;
            cs += clsPart[idx]; rs += regPart[idx]; ps += posPart[idx];
        }
    }
    #pragma unroll
    for (int off = 32; off > 0; off >>= 1) {
        cs += __shfl_down(cs, off);
        rs += __shfl_down(rs, off);
        ps += __shfl_down(ps, off);
    }
    __shared__ double s_c[kMaxB];
    __shared__ double s_r[kMaxB];
    __shared__ int    s_p[kMaxB];
    if (l == 0 && w < B) { s_c[w] = cs; s_r[w] = rs; s_p[w] = ps; }
    __syncthreads();
    if (threadIdx.x == 0) {
        double co = 0.0, ro = 0.0;
        for (int b = 0; b < B; ++b) {
            double np = (double)s_p[b];
            co += s_c[b] / fmax(np, 1.0);
            ro += (s_p[b] > 0) ? s_r[b] / (np * 4.0) : 0.0;
        }
        out[0] = (float)(co / B);
        out[1] = (float)(ro / B);
    }
}

// ---------------- launch -----------------------------------------------------
extern "C" void kernel_launch(void* const* d_in, const int* in_sizes, int n_in,
                              void* d_out, int out_size, void* d_ws, size_t ws_size,
                              hipStream_t stream)
{
    const float* cls = (const float*)d_in[0];   // [B, A, C]
    const float* reg = (const float*)d_in[1];   // [B, A, 4]
    const float* anc = (const float*)d_in[2];   // [1, A, 4]
    const float* ann = (const float*)d_in[3];   // [B, M, 5]

    const int A = in_sizes[2] / 4;
    const int B = in_sizes[1] / (A * 4);
    const int M = in_sizes[3] / (B * 5);        // <= kMaxM

    const int nBlkX = A / kTA;                  // 256 for A=65536
    const int nPart = B * nBlkX;

    float* clsPart = (float*)d_ws;              // [nPart]
    float* regPart = clsPart + nPart;           // [nPart]
    int*   posPart = (int*)(regPart + nPart);   // [nPart]
    float* out     = (float*)d_out;

    dim3 grid(nBlkX, B);
    hipLaunchKernelGGL(focal_main, grid, dim3(kBlock), 0, stream,
                       cls, reg, anc, ann, clsPart, regPart, posPart, A, M);

    hipLaunchKernelGGL(finalize_kernel, dim3(1), dim3(64 * B), 0, stream,
                       clsPart, regPart, posPart, out, nBlkX, B);
}

// Round 4
// 242.058 us; speedup vs baseline: 1.0566x; 1.0256x over previous
//
#include <hip/hip_runtime.h>
#include <math.h>

// RetinaNet focal loss, B=8, A=65536, C=80, M=32.
// Memory-bound on classifications (167.8 MB). Fused streaming pass.
// R4 changes vs R3: (1) issue the first cls-tile load BEFORE phase-1 so the
// HBM stream starts immediately; (2) manual double-buffer prefetch in the
// phase-2 loop (load i+1 while computing i). No arithmetic changes.

typedef float f32x4 __attribute__((ext_vector_type(4)));

static constexpr int   kC     = 80;    // classes (fixed by reference)
static constexpr int   kTA    = 256;   // anchors per block (A % 256 == 0)
static constexpr int   kBlock = 256;   // threads per block
static constexpr int   kMaxM  = 32;    // max gt boxes per image
static constexpr int   kMaxB  = 16;    // max batch (actual 8)

// ---------------- per-element focal loss ------------------------------------
__device__ __forceinline__ float elem_loss(float c, int k, int f) {
    // f: assigned label if positive, -2 if negative (all-zero targets);
    //    ignore (-1) handled by caller.
    c = fminf(fmaxf(c, 1e-4f), 1.0f - 1e-4f);
    bool one = (k == f);
    float w = one ? (1.0f - c) : c;          // focal weight base
    float l = one ? c : (1.0f - c);          // bce argument
    // ALPHA = 0.5 -> alpha factor is 0.5 for both branches.
    return 0.5f * w * w * (-__logf(l));
}

// ---------------- main kernel -----------------------------------------------
__global__ __launch_bounds__(kBlock) void focal_main(
        const float* __restrict__ cls,   // [B, A, C]
        const float* __restrict__ reg,   // [B, A, 4]
        const float* __restrict__ anc,   // [A, 4]
        const float* __restrict__ ann,   // [B, M, 5]
        float* __restrict__ clsPart,     // [B * gridDim.x]
        float* __restrict__ regPart,     // [B * gridDim.x]
        int*   __restrict__ posPart,     // [B * gridDim.x]
        int A, int M)
{
    const int b  = blockIdx.y;
    const int a0 = blockIdx.x * kTA;
    const int t  = threadIdx.x;

    __shared__ float s_box[kMaxM][6];    // x1,y1,x2,y2,area,label
    __shared__ int   s_flag[kTA];        // label | -2 (neg) | -1 (ignore)

    // ---- start the cls HBM stream NOW (result consumed after the barrier) --
    const f32x4* cbase =
        reinterpret_cast<const f32x4*>(cls + ((size_t)b * A + a0) * kC);
    f32x4 cur = __builtin_nontemporal_load(&cbase[t]);      // iteration 0

    if (t < M) {
        const float* p = ann + ((size_t)b * M + t) * 5;
        float x1 = p[0], y1 = p[1], x2 = p[2], y2 = p[3], lb = p[4];
        s_box[t][0] = x1; s_box[t][1] = y1;
        s_box[t][2] = x2; s_box[t][3] = y2;
        s_box[t][4] = (x2 - x1) * (y2 - y1);   // area_b
        s_box[t][5] = lb;
    }
    __syncthreads();

    // ---- phase 1: one anchor per thread: IoU argmax + flags + reg loss ----
    const int a = a0 + t;
    const f32x4 ab = *reinterpret_cast<const f32x4*>(anc + (size_t)a * 4);
    const float aw = ab.z - ab.x;
    const float ah = ab.w - ab.y;
    const float area_a = aw * ah;

    float best = -1.0f;
    int bestj = 0;
    #pragma unroll 8
    for (int j = 0; j < M; ++j) {
        float iw = fminf(ab.z, s_box[j][2]) - fmaxf(ab.x, s_box[j][0]);
        float ih = fminf(ab.w, s_box[j][3]) - fmaxf(ab.y, s_box[j][1]);
        iw = fmaxf(iw, 0.0f);
        ih = fmaxf(ih, 0.0f);
        float inter = iw * ih;
        float ua = fmaxf(area_a + s_box[j][4] - inter, 1e-8f);
        float iou = inter / ua;
        if (iou > best) { best = iou; bestj = j; }   // first-max semantics
    }
    const bool pos = (best >= 0.5f);
    const int flag = pos ? (int)s_box[bestj][5] : ((best < 0.4f) ? -2 : -1);
    s_flag[t] = flag;

    float regLoss = 0.0f;
    int   posInt  = pos ? 1 : 0;
    if (pos) {
        float gx1 = s_box[bestj][0], gy1 = s_box[bestj][1];
        float gx2 = s_box[bestj][2], gy2 = s_box[bestj][3];
        float gw = gx2 - gx1, gh = gy2 - gy1;
        float gcx = gx1 + 0.5f * gw, gcy = gy1 + 0.5f * gh;  // unclamped ctrs
        gw = fmaxf(gw, 1.0f);
        gh = fmaxf(gh, 1.0f);
        float acx = ab.x + 0.5f * aw, acy = ab.y + 0.5f * ah;
        float t0 = ((gcx - acx) / aw) / 0.1f;
        float t1 = ((gcy - acy) / ah) / 0.1f;
        float t2 = logf(gw / aw) / 0.2f;
        float t3 = logf(gh / ah) / 0.2f;
        const f32x4 rg = __builtin_nontemporal_load(
            reinterpret_cast<const f32x4*>(reg + ((size_t)b * A + a) * 4));
        float d0 = fabsf(t0 - rg.x), d1 = fabsf(t1 - rg.y);
        float d2 = fabsf(t2 - rg.z), d3 = fabsf(t3 - rg.w);
        const float th = 1.0f / 9.0f, csh = 0.5f / 9.0f;
        regLoss  = (d0 <= th) ? 4.5f * d0 * d0 : d0 - csh;
        regLoss += (d1 <= th) ? 4.5f * d1 * d1 : d1 - csh;
        regLoss += (d2 <= th) ? 4.5f * d2 * d2 : d2 - csh;
        regLoss += (d3 <= th) ? 4.5f * d3 * d3 : d3 - csh;
    }
    __syncthreads();

    // ---- phase 2: double-buffered nontemporal f32x4 stream over cls tile --
    constexpr int F4A  = kC / 4;                    // 20 f32x4 per anchor
    constexpr int ITER = kTA * F4A / kBlock;        // 20 iterations
    float clsLoss = 0.0f;
    #pragma unroll 4
    for (int i = 0; i < ITER; ++i) {
        const f32x4 v = cur;
        if (i + 1 < ITER)
            cur = __builtin_nontemporal_load(&cbase[(i + 1) * kBlock + t]);
        int idx = i * kBlock + t;                   // f32x4 index in tile
        int al  = idx / F4A;                        // local anchor
        int kb  = (idx - al * F4A) * 4;             // class base
        int f   = s_flag[al];
        if (f != -1) {
            clsLoss += elem_loss(v.x, kb + 0, f);
            clsLoss += elem_loss(v.y, kb + 1, f);
            clsLoss += elem_loss(v.z, kb + 2, f);
            clsLoss += elem_loss(v.w, kb + 3, f);
        }
    }

    // ---- block reduce (wave shuffle, then cross-wave via LDS) ----
    #pragma unroll
    for (int off = 32; off > 0; off >>= 1) {
        clsLoss += __shfl_down(clsLoss, off);
        regLoss += __shfl_down(regLoss, off);
        posInt  += __shfl_down(posInt,  off);
    }
    __shared__ float s_cls[kBlock / 64];
    __shared__ float s_reg[kBlock / 64];
    __shared__ int   s_pos[kBlock / 64];
    const int wid = t >> 6, lane = t & 63;
    if (lane == 0) { s_cls[wid] = clsLoss; s_reg[wid] = regLoss; s_pos[wid] = posInt; }
    __syncthreads();
    if (t == 0) {
        float cs = 0.0f, rs = 0.0f; int ps = 0;
        #pragma unroll
        for (int w = 0; w < kBlock / 64; ++w) { cs += s_cls[w]; rs += s_reg[w]; ps += s_pos[w]; }
        const int part = b * gridDim.x + blockIdx.x;   // unique slot per block
        clsPart[part] = cs;
        regPart[part] = rs;
        posPart[part] = ps;
    }
}

// ---------------- finalize: reduce partials, write the two outputs ----------
__global__ void finalize_kernel(const float* __restrict__ clsPart,
                                const float* __restrict__ regPart,
                                const int*   __restrict__ posPart,
                                float* __restrict__ out,
                                int nPerImg, int B)
{
    const int w = threadIdx.x >> 6;     // wave id = image id
    const int l = threadIdx.x & 63;
    float cs = 0.0f, rs = 0.0f; int ps = 0;
    if (w < B) {
        for (int i = l; i < nPerImg; i += 64) {
            int idx = w * nPerImg + i;
            cs += clsPart[idx]; rs += regPart[idx]; ps += posPart[idx];
        }
    }
    #pragma unroll
    for (int off = 32; off > 0; off >>= 1) {
        cs += __shfl_down(cs, off);
        rs += __shfl_down(rs, off);
        ps += __shfl_down(ps, off);
    }
    __shared__ double s_c[kMaxB];
    __shared__ double s_r[kMaxB];
    __shared__ int    s_p[kMaxB];
    if (l == 0 && w < B) { s_c[w] = cs; s_r[w] = rs; s_p[w] = ps; }
    __syncthreads();
    if (threadIdx.x == 0) {
        double co = 0.0, ro = 0.0;
        for (int b = 0; b < B; ++b) {
            double np = (double)s_p[b];
            co += s_c[b] / fmax(np, 1.0);
            ro += (s_p[b] > 0) ? s_r[b] / (np * 4.0) : 0.0;
        }
        out[0] = (float)(co / B);
        out[1] = (float)(ro / B);
    }
}

// ---------------- launch -----------------------------------------------------
extern "C" void kernel_launch(void* const* d_in, const int* in_sizes, int n_in,
                              void* d_out, int out_size, void* d_ws, size_t ws_size,
                              hipStream_t stream)
{
    const float* cls = (const float*)d_in[0];   // [B, A, C]
    const float* reg = (const float*)d_in[1];   // [B, A, 4]
    const float* anc = (const float*)d_in[2];   // [1, A, 4]
    const float* ann = (const float*)d_in[3];   // [B, M, 5]

    const int A = in_sizes[2] / 4;
    const int B = in_sizes[1] / (A * 4);
    const int M = in_sizes[3] / (B * 5);        // <= kMaxM

    const int nBlkX = A / kTA;                  // 256 for A=65536
    const int nPart = B * nBlkX;

    float* clsPart = (float*)d_ws;              // [nPart]
    float* regPart = clsPart + nPart;           // [nPart]
    int*   posPart = (int*)(regPart + nPart);   // [nPart]
    float* out     = (float*)d_out;

    dim3 grid(nBlkX, B);
    hipLaunchKernelGGL(focal_main, grid, dim3(kBlock), 0, stream,
                       cls, reg, anc, ann, clsPart, regPart, posPart, A, M);

    hipLaunchKernelGGL(finalize_kernel, dim3(1), dim3(64 * B), 0, stream,
                       clsPart, regPart, posPart, out, nBlkX, B);
}